// Round 9
// baseline (111.363 us; speedup 1.0000x reference)
//
#include <hip/hip_runtime.h>

#define BB 16
#define HIMG 64
#define WIMG 64
#define CC 256
#define NHEAD 8
#define HD 32
#define NN 4096
#define PWD 65   // 2*DH+1
#define PADC 264 // qr_bf row stride (ushorts): 528B row = 2-way-free LDS banking

typedef short bf16x8 __attribute__((ext_vector_type(8)));
typedef float f32x4 __attribute__((ext_vector_type(4)));

__device__ __forceinline__ float elu1(float x) {
    return x > 0.0f ? x + 1.0f : __expf(x);
}
__device__ __forceinline__ float sigm(float x) {
    return 1.0f / (1.0f + __expf(-x));
}
__device__ __forceinline__ unsigned short f2bf(float f) {
    union { float f; unsigned int u; } v; v.f = f;
    unsigned int r = v.u + 0x7FFFu + ((v.u >> 16) & 1u);   // RNE
    return (unsigned short)(r >> 16);
}

// ---------------- Kernel 0: pw[n][c] = sigmoid(posw[i+1][j+1][c]) ---------------
__global__ __launch_bounds__(256) void k0_pw(
    const float* __restrict__ posw, float* __restrict__ pw)
{
    const int gid = blockIdx.x * 256 + threadIdx.x;  // 0 .. 262143
    const int n = gid >> 6;
    const int p = gid & 63;
    const int ii = n >> 6, jj = n & 63;
    const float4 v = *(const float4*)(posw + (size_t)((ii + 1) * PWD + (jj + 1)) * CC + p * 4);
    float4 r;
    r.x = sigm(v.x); r.y = sigm(v.y); r.z = sigm(v.z); r.w = sigm(v.w);
    *(float4*)(pw + (size_t)n * CC + p * 4) = r;
}

// ---------------- Kernel 1: partial kv (K_rope^T V) and ksum per chunk ----------
// grid = B * nch, block = 256 (4 waves). 8-row steps, 2-deep register prefetch,
// raw s_barrier + lgkmcnt(0) only (global loads stay in flight across barriers).

#define K1_ISSUE(sS, kxS, pvS, vxS)                                          \
    do {                                                                      \
        const int r0_ = n0 + (sS) * 8;                                        \
        const int na_ = r0_ + w, nb_ = r0_ + w + 4;                           \
        kxS[0] = *(const float4*)(x2b + (size_t)na_ * CC + slot * 4);         \
        kxS[1] = *(const float4*)(x2b + (size_t)nb_ * CC + slot * 4);         \
        pvS[0] = *(const float4*)(pw  + (size_t)na_ * CC + slot * 4);         \
        pvS[1] = *(const float4*)(pw  + (size_t)nb_ * CC + slot * 4);         \
        vxS[0] = *(const float4*)(x3b + (size_t)na_ * CC + slot * 4);         \
        vxS[1] = *(const float4*)(x3b + (size_t)nb_ * CC + slot * 4);         \
    } while (0)

#define K1_STEP(sS, kxS, pvS, vxS, bufS)                                      \
    do {                                                                      \
        _Pragma("unroll")                                                     \
        for (int rp_ = 0; rp_ < 2; ++rp_) {                                   \
            const int row_ = w + rp_ * 4;                                     \
            float4 kk_;                                                       \
            kk_.x = elu1(kxS[rp_].x); kk_.y = elu1(kxS[rp_].y);               \
            kk_.z = elu1(kxS[rp_].z); kk_.w = elu1(kxS[rp_].w);               \
            ks0 += kk_.x; ks1 += kk_.y; ks2 += kk_.z; ks3 += kk_.w;           \
            float4 kr_;                                                       \
            kr_.x = kk_.x * pvS[rp_].x; kr_.y = kk_.y * pvS[rp_].y;           \
            kr_.z = kk_.z * pvS[rp_].z; kr_.w = kk_.w * pvS[rp_].w;           \
            *(float4*)(&kr_lds[bufS][row_][slot * 4]) = kr_;                  \
            *(float4*)(&v_lds[bufS][row_][slot * 4]) = vxS[rp_];              \
        }                                                                     \
        asm volatile("s_waitcnt lgkmcnt(0)" ::: "memory");                    \
        __builtin_amdgcn_s_barrier();                                         \
        if ((sS) + 2 < nstep) K1_ISSUE((sS) + 2, kxS, pvS, vxS);              \
        _Pragma("unroll")                                                     \
        for (int r_ = 0; r_ < 8; ++r_) {                                      \
            const float4 k4_ = *(const float4*)(&kr_lds[bufS][r_][h * HD + dt * 4]);   \
            const float4 va_ = *(const float4*)(&v_lds[bufS][r_][h * HD + et * 8]);    \
            const float4 vb_ = *(const float4*)(&v_lds[bufS][r_][h * HD + et * 8 + 4]);\
            const float kd_[4] = {k4_.x, k4_.y, k4_.z, k4_.w};                \
            const float ve_[8] = {va_.x, va_.y, va_.z, va_.w,                 \
                                  vb_.x, vb_.y, vb_.z, vb_.w};                \
            _Pragma("unroll")                                                 \
            for (int a_ = 0; a_ < 4; ++a_)                                    \
                _Pragma("unroll")                                             \
                for (int e_ = 0; e_ < 8; ++e_)                                \
                    acc[a_][e_] = fmaf(kd_[a_], ve_[e_], acc[a_][e_]);        \
        }                                                                     \
    } while (0)

__global__ __launch_bounds__(256, 2) void k1_partial(
    const float* __restrict__ x2, const float* __restrict__ x3,
    const float* __restrict__ pw, float* __restrict__ pkv,
    float* __restrict__ pksum, int nchl, int rows)
{
    const int blk   = blockIdx.x;
    const int b     = blk >> nchl;
    const int chunk = blk & ((1 << nchl) - 1);
    const int n0    = chunk * rows;
    const int t     = threadIdx.x;
    const int w     = t >> 6;      // wave id 0..3: loads rows {w, w+4} of each step
    const int slot  = t & 63;      // float4 slot

    const int h   = t >> 5;        // compute mapping: head
    const int idx = t & 31;
    const int dt  = idx & 7;
    const int et  = idx >> 3;

    __shared__ float kr_lds[2][8][CC];   // 16 KiB
    __shared__ float v_lds[2][8][CC];    // 16 KiB
    __shared__ float ksum_lds[4][CC];    // 4 KiB

    float acc[4][8];
#pragma unroll
    for (int a = 0; a < 4; ++a)
#pragma unroll
        for (int e = 0; e < 8; ++e) acc[a][e] = 0.0f;
    float ks0 = 0.f, ks1 = 0.f, ks2 = 0.f, ks3 = 0.f;

    const float* x2b = x2 + (size_t)b * NN * CC;
    const float* x3b = x3 + (size_t)b * NN * CC;

    const int nstep = rows >> 3;   // 8 rows per step; rows=64/128 -> nstep even

    float4 kx0[2], pv0[2], vx0[2];
    float4 kx1[2], pv1[2], vx1[2];

    K1_ISSUE(0, kx0, pv0, vx0);
    K1_ISSUE(1, kx1, pv1, vx1);

    for (int s = 0; s < nstep; s += 2) {
        K1_STEP(s,     kx0, pv0, vx0, 0);
        K1_STEP(s + 1, kx1, pv1, vx1, 1);
    }

    ksum_lds[w][slot * 4 + 0] = ks0;
    ksum_lds[w][slot * 4 + 1] = ks1;
    ksum_lds[w][slot * 4 + 2] = ks2;
    ksum_lds[w][slot * 4 + 3] = ks3;
    __syncthreads();
    pksum[(size_t)blk * CC + t] = ksum_lds[0][t] + ksum_lds[1][t] +
                                  ksum_lds[2][t] + ksum_lds[3][t];

    float* dst = pkv + (size_t)blk * (NHEAD * HD * HD);
#pragma unroll
    for (int a = 0; a < 4; ++a)
#pragma unroll
        for (int e = 0; e < 8; ++e)
            dst[h * (HD * HD) + (dt * 4 + a) * HD + (et * 8 + e)] = acc[a][e];
}

// ---------------- Kernel 2: reduce partials; emit kvbT (bf16, [b][h][e][d]) -----
// grid = 512, block = 256
__global__ __launch_bounds__(256) void k2_reduce(
    const float* __restrict__ pkv, const float* __restrict__ pksum,
    unsigned short* __restrict__ kvbT, float* __restrict__ kmean, int nch)
{
    const int gid = blockIdx.x * 256 + threadIdx.x;   // over B*8192
    const int b = gid >> 13;
    const int o = gid & 8191;
    float s = 0.f;
#pragma unroll 4
    for (int c = 0; c < nch; ++c)
        s += pkv[(size_t)(b * nch + c) * (NHEAD * HD * HD) + o];
    const int hh = o >> 10, d = (o >> 5) & 31, e = o & 31;
    kvbT[(((size_t)b * NHEAD + hh) * HD + e) * HD + d] = f2bf(s * (1.0f / NN));
    if (o < CC) {
        float ss = 0.f;
#pragma unroll 4
        for (int c = 0; c < nch; ++c)
            ss += pksum[(size_t)(b * nch + c) * CC + o];
        kmean[b * CC + o] = ss * (1.0f / NN);
    }
}

// ---------------- Kernel 3: out = MFMA((qr*z) @ kv) + LePE ----------------------
// grid = B*256 (quarter image row each), block = 256 (4 waves)
__global__ __launch_bounds__(256, 2) void k3_out(
    const float* __restrict__ x1, const float* __restrict__ x3,
    const float* __restrict__ pw, const unsigned short* __restrict__ kvbT,
    const float* __restrict__ kmean, const float* __restrict__ lw,
    const float* __restrict__ lb, float* __restrict__ out)
{
    const int blk  = blockIdx.x;      // b*256 + irow*4 + jq
    const int b    = blk >> 8;
    const int irow = (blk >> 2) & 63;
    const int jq   = blk & 3;
    const int j0   = jq << 4;         // 0, 16, 32, 48
    const int t    = threadIdx.x;

    __shared__ unsigned short qr_bf[16 * PADC];   // (qr * z) in bf16, 8.4 KiB
    __shared__ float attn_lds[16][CC];            // 16 KiB

    float wreg[9];
#pragma unroll
    for (int q = 0; q < 9; ++q) wreg[q] = lw[t * 9 + q];
    const float bias = lb[t];

    // ---- stage: q_rope * z  -> bf16 LDS (z folded in; known after shfl reduce) ----
    {
        const int p    = t & 63;       // float4 slot within a pixel's 256 channels
        const int pixo = t >> 6;       // 0..3
        const float4 km4 = *(const float4*)(kmean + b * CC + p * 4);
        const float* x1b = x1 + ((size_t)b * NN + (size_t)irow * 64 + j0) * CC;
        const float* pwb = pw + ((size_t)irow * 64 + j0) * CC;
        float4 xv[4], pvv[4];
#pragma unroll
        for (int s = 0; s < 4; ++s)
            xv[s] = *(const float4*)(x1b + (size_t)(s * 4 + pixo) * CC + p * 4);
#pragma unroll
        for (int s = 0; s < 4; ++s)
            pvv[s] = *(const float4*)(pwb + (size_t)(s * 4 + pixo) * CC + p * 4);
#pragma unroll
        for (int s = 0; s < 4; ++s) {
            const int pix = s * 4 + pixo;   // 0..15 (local)
            float4 q4;
            q4.x = elu1(xv[s].x); q4.y = elu1(xv[s].y);
            q4.z = elu1(xv[s].z); q4.w = elu1(xv[s].w);
            float zp = q4.x * km4.x + q4.y * km4.y + q4.z * km4.z + q4.w * km4.w;
            zp += __shfl_xor(zp, 1);
            zp += __shfl_xor(zp, 2);
            zp += __shfl_xor(zp, 4);        // all 8 lanes of this head have the sum
            const float zin = 1.0f / (zp + 1e-6f);
            ushort4 u;
            u.x = f2bf(q4.x * pvv[s].x * zin);
            u.y = f2bf(q4.y * pvv[s].y * zin);
            u.z = f2bf(q4.z * pvv[s].z * zin);
            u.w = f2bf(q4.w * pvv[s].w * zin);
            *(ushort4*)(&qr_bf[pix * PADC + p * 4]) = u;
        }
    }

    // ---- halo loads issued BEFORE the barrier: cannot be sunk past it ----
    const bool hasU = irow > 0, hasD = irow < 63;
    const float* rU = x3 + ((size_t)b * NN + (size_t)(irow - 1) * 64 + j0) * CC + t;
    const float* rM = x3 + ((size_t)b * NN + (size_t)irow * 64 + j0) * CC + t;
    const float* rD = x3 + ((size_t)b * NN + (size_t)(irow + 1) * 64 + j0) * CC + t;

    float cu[2][10], cm[2][10], cd[2][10];
#pragma unroll
    for (int tt = 0; tt < 2; ++tt)
#pragma unroll
        for (int q = 0; q < 10; ++q) {
            const int col = tt * 8 + q - 1;     // local col in [-1, 16]
            const int g   = j0 + col;           // global col in [-1, 64]
            const bool ok = (g >= 0) && (g < 64);
            const long off = (long)col * CC;
            cm[tt][q] = ok ? rM[off] : 0.f;
            cu[tt][q] = (ok && hasU) ? rU[off] : 0.f;
            cd[tt][q] = (ok && hasD) ? rD[off] : 0.f;
        }

    __syncthreads();

    // ---- MFMA phase: wave w covers heads 2w,2w+1 over all 16 pixels ----
    {
        const int w  = t >> 6;
        const int l  = t & 63;
        const int lr = l & 15;     // A row (pixel) / B col / D col
        const int lg = l >> 4;     // k-group

        bf16x8 af0 = *(const bf16x8*)(&qr_bf[lr * PADC + (w * 2 + 0) * HD + lg * 8]);
        bf16x8 af1 = *(const bf16x8*)(&qr_bf[lr * PADC + (w * 2 + 1) * HD + lg * 8]);

        f32x4 acc[4];
#pragma unroll
        for (int ct = 0; ct < 4; ++ct) {
            const int head = w * 2 + (ct >> 1);
            const int cl   = (ct & 1) * 16 + lr;
            const bf16x8 bf = *(const bf16x8*)(kvbT +
                (((size_t)b * NHEAD + head) * HD + cl) * HD + lg * 8);
            f32x4 z4 = {0.f, 0.f, 0.f, 0.f};
            acc[ct] = __builtin_amdgcn_mfma_f32_16x16x32_bf16(
                (ct < 2) ? af0 : af1, bf, z4, 0, 0, 0);
        }
#pragma unroll
        for (int ct = 0; ct < 4; ++ct) {
            const int c = (w * 2 + (ct >> 1)) * HD + (ct & 1) * 16 + lr;
#pragma unroll
            for (int r = 0; r < 4; ++r)
                attn_lds[lg * 4 + r][c] = acc[ct][r];
        }
    }

    __syncthreads();

    // ---- epilogue: lepe (registers already loaded) + attn + store ----
    float* ob = out + ((size_t)b * NN + (size_t)irow * 64 + j0) * CC + t;
#pragma unroll
    for (int tt = 0; tt < 2; ++tt) {
#pragma unroll
        for (int q = 0; q < 8; ++q) {
            const int jl = tt * 8 + q;          // local pixel 0..15
            float lepe = bias
                + wreg[0] * cu[tt][q] + wreg[1] * cu[tt][q + 1] + wreg[2] * cu[tt][q + 2]
                + wreg[3] * cm[tt][q] + wreg[4] * cm[tt][q + 1] + wreg[5] * cm[tt][q + 2]
                + wreg[6] * cd[tt][q] + wreg[7] * cd[tt][q + 1] + wreg[8] * cd[tt][q + 2];
            __builtin_nontemporal_store(attn_lds[jl][t] + lepe, ob + (long)jl * CC);
        }
    }
}

extern "C" void kernel_launch(void* const* d_in, const int* in_sizes, int n_in,
                              void* d_out, int out_size, void* d_ws, size_t ws_size,
                              hipStream_t stream) {
    const float* x1   = (const float*)d_in[0];
    const float* x2   = (const float*)d_in[1];
    const float* x3   = (const float*)d_in[2];
    const float* posw = (const float*)d_in[3];
    const float* lw   = (const float*)d_in[4];
    const float* lb   = (const float*)d_in[5];
    float* out = (float*)d_out;

    // ws layout: pw | pkv | pksum | kmean | kvbT(ushort)
    const size_t pw_sz = (size_t)NN * CC;                       // 1M floats
    const size_t need64 = (pw_sz + (size_t)16 * 64 * 8192 + (size_t)16 * 64 * 256 +
                           (size_t)16 * 256) * sizeof(float) +
                          (size_t)16 * 8192 * sizeof(unsigned short);
    const int nchl = (ws_size >= need64) ? 6 : 5;
    const int nch  = 1 << nchl;
    const int rows = NN >> nchl;

    float* pwb   = (float*)d_ws;
    float* pkv   = pwb + pw_sz;                        // 16*nch * 8192
    float* pksum = pkv + (size_t)16 * nch * 8192;      // 16*nch * 256
    float* kmean = pksum + (size_t)16 * nch * 256;     // 16 * 256
    unsigned short* kvbT = (unsigned short*)(kmean + (size_t)16 * 256);  // 16*8192

    k0_pw<<<1024, 256, 0, stream>>>(posw, pwb);
    k1_partial<<<16 * nch, 256, 0, stream>>>(x2, x3, pwb, pkv, pksum, nchl, rows);
    k2_reduce<<<512, 256, 0, stream>>>(pkv, pksum, kvbT, kmean, nch);
    k3_out<<<BB * 256, 256, 0, stream>>>(x1, x3, pwb, kvbT, kmean, lw, lb, out);
}